// Round 5
// baseline (971.843 us; speedup 1.0000x reference)
//
#include <hip/hip_runtime.h>

static constexpr int NN = 131072;   // nodes
static constexpr int NE = 524288;   // edges
static constexpr int NG = 4096;     // graphs

typedef __attribute__((ext_vector_type(8))) short short8;
typedef __attribute__((ext_vector_type(4))) float f32x4;

__device__ __forceinline__ float bfbits2f(unsigned b) {
    return __uint_as_float(b << 16);
}
__device__ __forceinline__ unsigned short f2bfbits(float f) {
    unsigned u = __float_as_uint(f);
    u += 0x7fffu + ((u >> 16) & 1u);   // RNE
    return (unsigned short)(u >> 16);
}
__device__ __forceinline__ unsigned pack2(float a, float b) {
    return (unsigned)f2bfbits(a) | ((unsigned)f2bfbits(b) << 16);
}

// dual-width integer read (robust to int32 or int64 index tensors)
__device__ __forceinline__ int geti(const void* p, size_t i, int w64) {
    return w64 ? (int)((const long long*)p)[i] : ((const int*)p)[i];
}

// ---- hand-rolled OCP e4m3 codec ----
__device__ __forceinline__ float e4m32f(unsigned b) {
    unsigned e = (b >> 3) & 0xFu, m = b & 7u;
    float v = e ? __uint_as_float(((e + 120u) << 23) | (m << 20))
                : (float)m * 0.001953125f;            // m * 2^-9
    return (b & 0x80u) ? -v : v;
}
__device__ __forceinline__ unsigned f2e4m3(float f) {
    unsigned u = __float_as_uint(f);
    unsigned s = (u >> 24) & 0x80u;
    unsigned mag = u & 0x7fffffffu;
    if (mag >= 0x43e00000u) return s | 0x7eu;          // clamp to +-448
    if (mag < 0x3c800000u) {                           // |f| < 2^-6 -> subnormal
        int q = (int)(__uint_as_float(mag) * 512.0f + 0.5f);   // 0..8
        return s | (unsigned)q;
    }
    unsigned r = mag + 0x0007ffffu + ((mag >> 20) & 1u);       // RNE to 3 mant bits
    if (r >= 0x43e00000u) return s | 0x7eu;
    return s | (((r >> 23) - 120u) << 3) | ((r >> 20) & 7u);
}

// ---------------- detect int width (int64 => odd int32 halves are zero) ----------------
__global__ void k_detect(const void* __restrict__ eidx, const void* __restrict__ batch,
                         int* __restrict__ flags) {
    const int* e32 = (const int*)eidx;
    const int* b32 = (const int*)batch;
    int e64 = (e32[1] == 0 && e32[2001] == 0 && e32[40001] == 0 && e32[2 * NE - 1] == 0) ? 1 : 0;
    int b64 = (b32[NN - 1] == 0) ? 1 : 0;
    flags[0] = e64;
    flags[1] = b64;
}

// ---------------- small prep kernels ----------------

__global__ void k_zero(int* __restrict__ p, int n) {
    int i = blockIdx.x * 256 + threadIdx.x;
    if (i < n) p[i] = 0;
}

// fp32 W[K,Ncols] -> bf16 Wt[Ncols,K]
__global__ void k_transpose(const float* __restrict__ W,
                            unsigned short* __restrict__ Wt, int K, int Ncols) {
    int idx = blockIdx.x * 256 + threadIdx.x;
    if (idx >= K * Ncols) return;
    int k = idx / Ncols, n = idx - k * Ncols;
    Wt[n * K + k] = f2bfbits(W[idx]);
}

__global__ void k_bn_prep(const float* __restrict__ g, const float* __restrict__ be,
                          const float* __restrict__ m, const float* __restrict__ v,
                          float* __restrict__ s, float* __restrict__ t, int d) {
    int i = blockIdx.x * 256 + threadIdx.x;
    if (i >= d) return;
    float inv = rsqrtf(v[i] + 1e-5f);
    float sc = g[i] * inv;
    s[i] = sc;
    t[i] = be[i] - m[i] * sc;
}

__global__ void k_deg_count(const void* __restrict__ eidx, const int* __restrict__ flags,
                            int* __restrict__ cnt) {
    int i = blockIdx.x * 256 + threadIdx.x;
    if (i >= NE) return;
    int d = geti(eidx, (size_t)NE + i, flags[0]);
    atomicAdd(&cnt[d], 1);
}

__global__ void k_dinv(const int* __restrict__ cnt, float* __restrict__ dinv) {
    int i = blockIdx.x * 256 + threadIdx.x;
    if (i < NN) dinv[i] = rsqrtf((float)(cnt[i] + 1));   // +1 self-loop
}

// single-block exclusive scan of cnt[NN] -> rowptr[NN+1]
__global__ __launch_bounds__(1024) void k_scan(const int* __restrict__ cnt, int* __restrict__ rowptr) {
    __shared__ int part[1024];
    const int t = threadIdx.x;
    const int base = t * 128;
    int s = 0;
    for (int i = 0; i < 128; ++i) s += cnt[base + i];
    part[t] = s;
    __syncthreads();
    for (int off = 1; off < 1024; off <<= 1) {
        int v = (t >= off) ? part[t - off] : 0;
        __syncthreads();
        part[t] += v;
        __syncthreads();
    }
    int ex = (t == 0) ? 0 : part[t - 1];
    for (int i = 0; i < 128; ++i) { rowptr[base + i] = ex; ex += cnt[base + i]; }
    if (t == 1023) rowptr[NN] = ex;
}

__global__ void k_fill(const void* __restrict__ eidx, const int* __restrict__ flags,
                       const int* __restrict__ rowptr, int* __restrict__ fillp,
                       int* __restrict__ col) {
    int i = blockIdx.x * 256 + threadIdx.x;
    if (i >= NE) return;
    int e64 = flags[0];
    int s = geti(eidx, (size_t)i, e64);
    int d = geti(eidx, (size_t)NE + i, e64);
    int p = rowptr[d] + atomicAdd(&fillp[d], 1);
    col[p] = s;
}

// batch sorted: graph g spans rows [gstart[g], gstart[g+1])
__global__ void k_gstart(const void* __restrict__ batch, const int* __restrict__ flags,
                         int* __restrict__ gstart) {
    int i = blockIdx.x * 256 + threadIdx.x;
    if (i >= NN) return;
    int b64 = flags[1];
    int b = geti(batch, (size_t)i, b64);
    if (i == 0) {
        for (int g = 0; g <= b; ++g) gstart[g] = 0;
    } else {
        int pb = geti(batch, (size_t)i - 1, b64);
        for (int g = pb + 1; g <= b; ++g) gstart[g] = i;
    }
    if (i == NN - 1) {
        for (int g = b + 1; g <= NG; ++g) gstart[g] = NN;
    }
}

// ---------------- row load/store helpers. IN_MODE: 0=bf16, 1=fp8, 2=fp32 ----------------
template<int D, int MODE>
__device__ __forceinline__ void load_row(const void* h, int sn, int c0, float* v) {
    constexpr int EPL = D / 64;
    if constexpr (MODE == 2) {                       // fp32
        const float* p = (const float*)h + (size_t)sn * D + c0;
#pragma unroll
        for (int i = 0; i < EPL; i += 2) {
            float2 u = *(const float2*)(p + i);
            v[i] = u.x; v[i + 1] = u.y;
        }
    } else if constexpr (MODE == 1) {                // fp8
        const unsigned char* p = (const unsigned char*)h + (size_t)sn * D + c0;
        if constexpr (EPL == 8) {
            uint2 u = *(const uint2*)p;
#pragma unroll
            for (int i = 0; i < 4; ++i) v[i] = e4m32f((u.x >> (8 * i)) & 0xffu);
#pragma unroll
            for (int i = 0; i < 4; ++i) v[4 + i] = e4m32f((u.y >> (8 * i)) & 0xffu);
        } else if constexpr (EPL == 4) {
            unsigned u = *(const unsigned*)p;
#pragma unroll
            for (int i = 0; i < 4; ++i) v[i] = e4m32f((u >> (8 * i)) & 0xffu);
        } else {
            unsigned short u = *(const unsigned short*)p;
            v[0] = e4m32f(u & 0xffu); v[1] = e4m32f((u >> 8) & 0xffu);
        }
    } else {                                         // bf16
        const unsigned short* p = (const unsigned short*)h + (size_t)sn * D + c0;
        if constexpr (EPL == 8) {
            uint4 u = *(const uint4*)p;
            unsigned w[4] = {u.x, u.y, u.z, u.w};
#pragma unroll
            for (int i = 0; i < 4; ++i) { v[2 * i] = bfbits2f(w[i] & 0xffffu); v[2 * i + 1] = bfbits2f(w[i] >> 16); }
        } else if constexpr (EPL == 4) {
            uint2 u = *(const uint2*)p;
            v[0] = bfbits2f(u.x & 0xffffu); v[1] = bfbits2f(u.x >> 16);
            v[2] = bfbits2f(u.y & 0xffffu); v[3] = bfbits2f(u.y >> 16);
        } else {
            unsigned u = *(const unsigned*)p;
            v[0] = bfbits2f(u & 0xffffu); v[1] = bfbits2f(u >> 16);
        }
    }
}

template<int D, bool FP8>
__device__ __forceinline__ void store_row(void* out, int n, int c0, const float* v) {
    constexpr int EPL = D / 64;
    if constexpr (FP8) {
        unsigned char* p = (unsigned char*)out + (size_t)n * D + c0;
        if constexpr (EPL == 8) {
            uint2 u;
            u.x = f2e4m3(v[0]) | (f2e4m3(v[1]) << 8) | (f2e4m3(v[2]) << 16) | (f2e4m3(v[3]) << 24);
            u.y = f2e4m3(v[4]) | (f2e4m3(v[5]) << 8) | (f2e4m3(v[6]) << 16) | (f2e4m3(v[7]) << 24);
            *(uint2*)p = u;
        } else if constexpr (EPL == 4) {
            *(unsigned*)p = f2e4m3(v[0]) | (f2e4m3(v[1]) << 8) | (f2e4m3(v[2]) << 16) | (f2e4m3(v[3]) << 24);
        } else {
            *(unsigned short*)p = (unsigned short)(f2e4m3(v[0]) | (f2e4m3(v[1]) << 8));
        }
    } else {
        unsigned short* p = (unsigned short*)out + (size_t)n * D + c0;
        if constexpr (EPL == 8) {
            uint4 u; u.x = pack2(v[0], v[1]); u.y = pack2(v[2], v[3]);
            u.z = pack2(v[4], v[5]); u.w = pack2(v[6], v[7]);
            *(uint4*)p = u;
        } else if constexpr (EPL == 4) {
            uint2 u; u.x = pack2(v[0], v[1]); u.y = pack2(v[2], v[3]);
            *(uint2*)p = u;
        } else {
            *(unsigned*)p = pack2(v[0], v[1]);
        }
    }
}

// ---------------- pull aggregation (CSR, fp32 reg accum) ----------------
template<int D, int IN_MODE, bool OUT_FP8, bool EPI>
__global__ __launch_bounds__(256) void k_agg(
    const void* __restrict__ h,
    const int* __restrict__ rowptr, const int* __restrict__ col,
    const float* __restrict__ dinv,
    const float* __restrict__ b, const float* __restrict__ s, const float* __restrict__ t,
    void* __restrict__ out)
{
    constexpr int EPL = D / 64;
    int n = (blockIdx.x * 256 + threadIdx.x) >> 6;
    int lane = threadIdx.x & 63;
    if (n >= NN) return;
    const int c0 = lane * EPL;
    float dn = dinv[n];
    float acc[EPL], vals[EPL];

    load_row<D, IN_MODE>(h, n, c0, vals);       // self loop: weight dinv[n]^2
    float wsl = dn * dn;
#pragma unroll
    for (int i = 0; i < EPL; ++i) acc[i] = vals[i] * wsl;

    int e1 = rowptr[n + 1];
    for (int e = rowptr[n]; e < e1; ++e) {
        int sn = col[e];
        float w = dinv[sn] * dn;
        load_row<D, IN_MODE>(h, sn, c0, vals);
#pragma unroll
        for (int i = 0; i < EPL; ++i) acc[i] += vals[i] * w;
    }

    if constexpr (EPI) {                        // layer-3 epilogue: bn(relu(z + bias))
#pragma unroll
        for (int i = 0; i < EPL; ++i) {
            int c = c0 + i;
            float z = acc[i] + b[c];
            z = fmaxf(z, 0.0f);
            acc[i] = s[c] * z + t[c];
        }
    }
    store_row<D, OUT_FP8>(out, n, c0, acc);
}

// ---------------- pooling: one wave per graph ----------------
__global__ void k_pool(const unsigned short* __restrict__ h3, const int* __restrict__ gstart,
                       unsigned short* __restrict__ pooled) {
    int g = (blockIdx.x * 256 + threadIdx.x) >> 6;
    int lane = threadIdx.x & 63;
    if (g >= NG) return;
    int r0 = gstart[g], r1 = gstart[g + 1];
    float a0 = 0, a1 = 0, a2 = 0, a3 = 0;
    for (int r = r0; r < r1; ++r) {
        uint2 u = *(const uint2*)(h3 + (size_t)r * 256 + lane * 4);
        a0 += bfbits2f(u.x & 0xffffu); a1 += bfbits2f(u.x >> 16);
        a2 += bfbits2f(u.y & 0xffffu); a3 += bfbits2f(u.y >> 16);
    }
    int c = r1 - r0;
    float inv = 1.0f / (float)(c > 0 ? c : 1);
    uint2 o;
    o.x = pack2(a0 * inv, a1 * inv);
    o.y = pack2(a2 * inv, a3 * inv);
    *(uint2*)(pooled + (size_t)g * 256 + lane * 4) = o;
}

// ---------------- MFMA GEMM: C[M,Ncols] = A[M,K] @ Wt[Ncols,K]^T, fused epilogue ----------------
// A_FP8: A operand fp8 (decode in staging). OUT_MODE: 0=bf16, 1=fp8, 2=fp32.
template<bool A_FP8, int OUT_MODE, bool RELU, bool HAS_BN, bool HAS_BIAS>
__global__ __launch_bounds__(256)
void k_gemm(const void* __restrict__ Aptr,
            const unsigned short* __restrict__ Wt,
            const float* __restrict__ bias,
            const float* __restrict__ s, const float* __restrict__ t,
            void* __restrict__ Cptr,
            int K, int Ncols)
{
    __shared__ __align__(16) unsigned short lA[128 * 40];   // stride 40: 2-way alias free (m136)
    __shared__ __align__(16) unsigned short lB[128 * 40];
    const int tid = threadIdx.x;
    const int bm = blockIdx.y * 128;
    const int bn = blockIdx.x * 128;
    const int lane = tid & 63;
    const int wave = tid >> 6;
    const int wm = (wave >> 1) * 64;
    const int wn = (wave & 1) * 64;
    const int fr = lane & 15;
    const int fq = lane >> 4;
    const int sr = tid >> 1;          // staging row 0..127
    const int sh = (tid & 1) * 16;    // 16-elem half of the 32-wide k tile

    f32x4 acc[4][4] = {};

    for (int k0 = 0; k0 < K; k0 += 32) {
        if constexpr (A_FP8) {
            const unsigned char* pa = (const unsigned char*)Aptr + (size_t)(bm + sr) * K + (k0 + sh);
            uint4 q = *(const uint4*)pa;          // 16 fp8
            unsigned w4[4] = {q.x, q.y, q.z, q.w};
            unsigned* da = (unsigned*)&lA[sr * 40 + sh];
#pragma unroll
            for (int wI = 0; wI < 4; ++wI) {
                unsigned W = w4[wI];
                da[2 * wI]     = pack2(e4m32f(W & 0xffu), e4m32f((W >> 8) & 0xffu));
                da[2 * wI + 1] = pack2(e4m32f((W >> 16) & 0xffu), e4m32f(W >> 24));
            }
        } else {
            const uint4* pa = (const uint4*)((const unsigned short*)Aptr + (size_t)(bm + sr) * K + (k0 + sh));
            uint4* da = (uint4*)&lA[sr * 40 + sh];
            da[0] = pa[0]; da[1] = pa[1];
        }
        {
            const uint4* pb = (const uint4*)(Wt + (size_t)(bn + sr) * K + (k0 + sh));
            uint4* db = (uint4*)&lB[sr * 40 + sh];
            db[0] = pb[0]; db[1] = pb[1];
        }
        __syncthreads();

        short8 a[4], b[4];
#pragma unroll
        for (int i = 0; i < 4; ++i)
            a[i] = *(const short8*)&lA[(wm + 16 * i + fr) * 40 + fq * 8];
#pragma unroll
        for (int j = 0; j < 4; ++j)
            b[j] = *(const short8*)&lB[(wn + 16 * j + fr) * 40 + fq * 8];
#pragma unroll
        for (int i = 0; i < 4; ++i)
#pragma unroll
            for (int j = 0; j < 4; ++j)
                acc[i][j] = __builtin_amdgcn_mfma_f32_16x16x32_bf16(a[i], b[j], acc[i][j], 0, 0, 0);
        __syncthreads();
    }

#pragma unroll
    for (int j = 0; j < 4; ++j) {
        int colI = bn + wn + 16 * j + fr;
        float bi = HAS_BIAS ? bias[colI] : 0.0f;
        float sc = HAS_BN ? s[colI] : 1.0f;
        float tc = HAS_BN ? t[colI] : 0.0f;
#pragma unroll
        for (int i = 0; i < 4; ++i) {
#pragma unroll
            for (int r = 0; r < 4; ++r) {
                int row = bm + wm + 16 * i + fq * 4 + r;
                float z = acc[i][j][r] + bi;
                if (RELU) z = fmaxf(z, 0.0f);
                float y = HAS_BN ? (sc * z + tc) : z;
                if constexpr (OUT_MODE == 2)
                    ((float*)Cptr)[(size_t)row * Ncols + colI] = y;
                else if constexpr (OUT_MODE == 1)
                    ((unsigned char*)Cptr)[(size_t)row * Ncols + colI] = (unsigned char)f2e4m3(y);
                else
                    ((unsigned short*)Cptr)[(size_t)row * Ncols + colI] = f2bfbits(y);
            }
        }
    }
}

// ---------------- launch ----------------

extern "C" void kernel_launch(void* const* d_in, const int* in_sizes, int n_in,
                              void* d_out, int out_size, void* d_ws, size_t ws_size,
                              hipStream_t stream) {
    const float* x   = (const float*)d_in[0];      // fp32 per reference
    const void* eidx = d_in[1];
    const void* batch = d_in[2];
    const float* W1  = (const float*)d_in[3];
    const float* b1  = (const float*)d_in[4];
    const float* W2  = (const float*)d_in[5];
    const float* b2  = (const float*)d_in[6];
    const float* W3  = (const float*)d_in[7];
    const float* b3  = (const float*)d_in[8];
    const float* g1  = (const float*)d_in[9];
    const float* be1 = (const float*)d_in[10];
    const float* m1  = (const float*)d_in[11];
    const float* v1  = (const float*)d_in[12];
    const float* g2  = (const float*)d_in[13];
    const float* be2 = (const float*)d_in[14];
    const float* m2  = (const float*)d_in[15];
    const float* v2  = (const float*)d_in[16];
    const float* g3  = (const float*)d_in[17];
    const float* be3 = (const float*)d_in[18];
    const float* m3  = (const float*)d_in[19];
    const float* v3  = (const float*)d_in[20];
    const float* Wf1 = (const float*)d_in[21];
    const float* bf1 = (const float*)d_in[22];
    const float* Wf2 = (const float*)d_in[23];
    const float* bf2 = (const float*)d_in[24];

    // ---- fixed compact layout (~139.6 MiB, identical extents to R4 = proven fault-free) ----
    unsigned char* RB = (unsigned char*)d_ws;            // 64 MiB: H1/H2 fp8 [NN,512]; later H3 bf16 [NN,256]
    unsigned char* RA = RB + 67108864;                   // 64 MiB: agg1 bf16 / agg2 fp8 / T3 bf16 / pooled+z1
    unsigned char* EX = RB + 134217728;                  // extras ~5.4 MiB
    int*   rowptr = (int*)(EX + 0);
    int*   col    = (int*)(EX + 524544);
    float* dinv   = (float*)(EX + 2621696);
    int*   cnt    = (int*)(EX + 3145984);
    int*   fillp  = (int*)(EX + 3670272);
    int*   gstart = (int*)(EX + 4194560);
    float* sbuf   = (float*)(EX + 4211456);
    float *s1 = sbuf, *t1 = sbuf + 512, *s2 = sbuf + 1024, *t2 = sbuf + 1536;
    float *s3 = sbuf + 2048, *t3v = sbuf + 2304;
    unsigned short* Wt1  = (unsigned short*)(EX + 4221696);  // [512,128] bf16
    unsigned short* Wt2  = (unsigned short*)(EX + 4352768);  // [512,512]
    unsigned short* Wt3  = (unsigned short*)(EX + 4877056);  // [256,512]
    unsigned short* Wtf1 = (unsigned short*)(EX + 5139200);  // [256,256]
    unsigned short* Wtf2 = (unsigned short*)(EX + 5270272);  // [256,256]
    int*   flags = (int*)(EX + 5401344);

    unsigned short* pooled = (unsigned short*)RA;            // [NG,256] bf16 (T3 dead)
    unsigned short* z1     = (unsigned short*)(RA + 2097152);

    // ---- prep ----
    k_detect<<<1, 1, 0, stream>>>(eidx, batch, flags);
    k_transpose<<<(128 * 512) / 256, 256, 0, stream>>>(W1, Wt1, 128, 512);
    k_transpose<<<(512 * 512) / 256, 256, 0, stream>>>(W2, Wt2, 512, 512);
    k_transpose<<<(512 * 256) / 256, 256, 0, stream>>>(W3, Wt3, 512, 256);
    k_transpose<<<(256 * 256) / 256, 256, 0, stream>>>(Wf1, Wtf1, 256, 256);
    k_transpose<<<(256 * 256) / 256, 256, 0, stream>>>(Wf2, Wtf2, 256, 256);
    k_bn_prep<<<2, 256, 0, stream>>>(g1, be1, m1, v1, s1, t1, 512);
    k_bn_prep<<<2, 256, 0, stream>>>(g2, be2, m2, v2, s2, t2, 512);
    k_bn_prep<<<1, 256, 0, stream>>>(g3, be3, m3, v3, s3, t3v, 256);
    k_zero<<<NN / 256, 256, 0, stream>>>(cnt, NN);
    k_zero<<<NN / 256, 256, 0, stream>>>(fillp, NN);
    k_deg_count<<<NE / 256, 256, 0, stream>>>(eidx, flags, cnt);
    k_dinv<<<NN / 256, 256, 0, stream>>>(cnt, dinv);
    k_scan<<<1, 1024, 0, stream>>>(cnt, rowptr);
    k_fill<<<NE / 256, 256, 0, stream>>>(eidx, flags, rowptr, fillp, col);
    k_gstart<<<NN / 256, 256, 0, stream>>>(batch, flags, gstart);

    const dim3 gagg(NN / 4), gpool(NG / 4);
    const dim3 ggA(4, NN / 128), ggB(2, NN / 128), ggh(2, NG / 128);

    // L1: agg x(fp32) @128 -> bf16 agg1 (RA); GEMM 128->512 +bias+relu+bn -> H1 fp8 (RB)
    k_agg<128, 2, false, false><<<gagg, 256, 0, stream>>>(x, rowptr, col, dinv, nullptr, nullptr, nullptr, RA);
    k_gemm<false, 1, true, true, true><<<ggA, 256, 0, stream>>>(RA, Wt1, b1, s1, t1, RB, 128, 512);

    // L2: agg H1(fp8) @512 -> agg2 fp8 (RA); GEMM 512->512 +epilogue -> H2 fp8 (RB)
    k_agg<512, 1, true, false><<<gagg, 256, 0, stream>>>(RB, rowptr, col, dinv, nullptr, nullptr, nullptr, RA);
    k_gemm<true, 1, true, true, true><<<ggA, 256, 0, stream>>>(RA, Wt2, b2, s2, t2, RB, 512, 512);

    // L3: GEMM 512->256 raw (H2 fp8 -> T3 bf16 in RA); agg @256 +fused epilogue -> H3 bf16 (RB)
    k_gemm<true, 0, false, false, false><<<ggB, 256, 0, stream>>>(RB, Wt3, nullptr, nullptr, nullptr, RA, 512, 256);
    k_agg<256, 0, false, true><<<gagg, 256, 0, stream>>>(RA, rowptr, col, dinv, b3, s3, t3v, RB);

    // pool (H3 in RB -> pooled bf16 in RA)
    k_pool<<<gpool, 256, 0, stream>>>((const unsigned short*)RB, gstart, pooled);

    // MLP head: z1 = relu(pooled@Wf1 + bf1); out(fp32) = z1@Wf2 + bf2
    k_gemm<false, 0, true, false, true><<<ggh, 256, 0, stream>>>(pooled, Wtf1, bf1, nullptr, nullptr, z1, 256, 256);
    k_gemm<false, 2, false, false, true><<<ggh, 256, 0, stream>>>(z1, Wtf2, bf2, nullptr, nullptr, d_out, 256, 256);
}

// Round 7
// 787.041 us; speedup vs baseline: 1.2348x; 1.2348x over previous
//
#include <hip/hip_runtime.h>

static constexpr int NN = 131072;   // nodes
static constexpr int NE = 524288;   // edges
static constexpr int NG = 4096;     // graphs

typedef __attribute__((ext_vector_type(8))) short short8;
typedef __attribute__((ext_vector_type(4))) float f32x4;
typedef __attribute__((ext_vector_type(2))) float f32x2;

__device__ __forceinline__ float bfbits2f(unsigned b) {
    return __uint_as_float(b << 16);
}
__device__ __forceinline__ unsigned short f2bfbits(float f) {
    unsigned u = __float_as_uint(f);
    u += 0x7fffu + ((u >> 16) & 1u);   // RNE
    return (unsigned short)(u >> 16);
}
__device__ __forceinline__ unsigned pack2(float a, float b) {
    return (unsigned)f2bfbits(a) | ((unsigned)f2bfbits(b) << 16);
}

// dual-width integer read (robust to int32 or int64 index tensors)
__device__ __forceinline__ int geti(const void* p, size_t i, int w64) {
    return w64 ? (int)((const long long*)p)[i] : ((const int*)p)[i];
}

#if __has_builtin(__builtin_amdgcn_cvt_pk_f32_fp8) && __has_builtin(__builtin_amdgcn_cvt_pk_fp8_f32)
#define FP8_CVT_HW 1
#else
#define FP8_CVT_HW 0
#endif

// ---- software OCP e4m3 codec (fallback + reference) ----
__device__ __forceinline__ float e4m32f(unsigned b) {
    unsigned e = (b >> 3) & 0xFu, m = b & 7u;
    float v = e ? __uint_as_float(((e + 120u) << 23) | (m << 20))
                : (float)m * 0.001953125f;            // m * 2^-9
    return (b & 0x80u) ? -v : v;
}
__device__ __forceinline__ unsigned f2e4m3(float f) {
    unsigned u = __float_as_uint(f);
    unsigned s = (u >> 24) & 0x80u;
    unsigned mag = u & 0x7fffffffu;
    if (mag >= 0x43e00000u) return s | 0x7eu;          // clamp to +-448
    if (mag < 0x3c800000u) {                           // |f| < 2^-6 -> subnormal
        int q = (int)(__uint_as_float(mag) * 512.0f + 0.5f);   // 0..8
        return s | (unsigned)q;
    }
    unsigned r = mag + 0x0007ffffu + ((mag >> 20) & 1u);       // RNE to 3 mant bits
    if (r >= 0x43e00000u) return s | 0x7eu;
    return s | (((r >> 23) - 120u) << 3) | ((r >> 20) & 7u);
}

// 2 fp8 (byte pair HI of dword w) -> packed bf16 dword. Exact: e4m3 subset of bf16.
// HI is a template param: the builtin's word-select must be an immediate.
template<bool HI>
__device__ __forceinline__ unsigned dec_pair(unsigned w) {
#if FP8_CVT_HW
    f32x2 p = __builtin_amdgcn_cvt_pk_f32_fp8((int)w, HI);
    return __builtin_amdgcn_perm(__float_as_uint(p.y), __float_as_uint(p.x), 0x07060302u);
#else
    unsigned b0 = HI ? ((w >> 16) & 255u) : (w & 255u);
    unsigned b1 = HI ? (w >> 24) : ((w >> 8) & 255u);
    return pack2(e4m32f(b0), e4m32f(b1));
#endif
}

// 8 fp8 -> short8 bf16 fragment
__device__ __forceinline__ short8 dec8(uint2 u) {
    union { uint4 q; short8 s; } r;
    r.q.x = dec_pair<false>(u.x);
    r.q.y = dec_pair<true>(u.x);
    r.q.z = dec_pair<false>(u.y);
    r.q.w = dec_pair<true>(u.y);
    return r.s;
}

__device__ __forceinline__ unsigned enc4(float a, float b, float c, float d) {
#if FP8_CVT_HW
    int r = __builtin_amdgcn_cvt_pk_fp8_f32(a, b, 0, false);
    r = __builtin_amdgcn_cvt_pk_fp8_f32(c, d, r, true);
    return (unsigned)r;
#else
    return f2e4m3(a) | (f2e4m3(b) << 8) | (f2e4m3(c) << 16) | (f2e4m3(d) << 24);
#endif
}
__device__ __forceinline__ unsigned enc1(float a) {
#if FP8_CVT_HW
    return (unsigned)__builtin_amdgcn_cvt_pk_fp8_f32(a, a, 0, false) & 0xffu;
#else
    return f2e4m3(a);
#endif
}

// async global->LDS, 16B/lane; data lands at l + lane*16
__device__ __forceinline__ void gld16(const void* g, void* l, int lane) {
#if __has_builtin(__builtin_amdgcn_global_load_lds)
    __builtin_amdgcn_global_load_lds((const __attribute__((address_space(1))) unsigned int*)g,
                                     (__attribute__((address_space(3))) unsigned int*)l, 16, 0, 0);
#else
    *(uint4*)((char*)l + lane * 16) = *(const uint4*)g;
#endif
}

// ---------------- detect int width (int64 => odd int32 halves are zero) ----------------
__global__ void k_detect(const void* __restrict__ eidx, const void* __restrict__ batch,
                         int* __restrict__ flags) {
    const int* e32 = (const int*)eidx;
    const int* b32 = (const int*)batch;
    int e64 = (e32[1] == 0 && e32[2001] == 0 && e32[40001] == 0 && e32[2 * NE - 1] == 0) ? 1 : 0;
    int b64 = (b32[NN - 1] == 0) ? 1 : 0;
    flags[0] = e64;
    flags[1] = b64;
}

// ---------------- small prep kernels ----------------

__global__ void k_zero(int* __restrict__ p, int n) {
    int i = blockIdx.x * 256 + threadIdx.x;
    if (i < n) p[i] = 0;
}

// fp32 W[K,Ncols] -> bf16 Wt[Ncols,K]
__global__ void k_transpose(const float* __restrict__ W,
                            unsigned short* __restrict__ Wt, int K, int Ncols) {
    int idx = blockIdx.x * 256 + threadIdx.x;
    if (idx >= K * Ncols) return;
    int k = idx / Ncols, n = idx - k * Ncols;
    Wt[n * K + k] = f2bfbits(W[idx]);
}

__global__ void k_bn_prep(const float* __restrict__ g, const float* __restrict__ be,
                          const float* __restrict__ m, const float* __restrict__ v,
                          float* __restrict__ s, float* __restrict__ t, int d) {
    int i = blockIdx.x * 256 + threadIdx.x;
    if (i >= d) return;
    float inv = rsqrtf(v[i] + 1e-5f);
    float sc = g[i] * inv;
    s[i] = sc;
    t[i] = be[i] - m[i] * sc;
}

__global__ void k_deg_count(const void* __restrict__ eidx, const int* __restrict__ flags,
                            int* __restrict__ cnt) {
    int i = blockIdx.x * 256 + threadIdx.x;
    if (i >= NE) return;
    int d = geti(eidx, (size_t)NE + i, flags[0]);
    atomicAdd(&cnt[d], 1);
}

__global__ void k_dinv(const int* __restrict__ cnt, float* __restrict__ dinv) {
    int i = blockIdx.x * 256 + threadIdx.x;
    if (i < NN) dinv[i] = rsqrtf((float)(cnt[i] + 1));   // +1 self-loop
}

// single-block exclusive scan of cnt[NN] -> rowptr[NN+1]
__global__ __launch_bounds__(1024) void k_scan(const int* __restrict__ cnt, int* __restrict__ rowptr) {
    __shared__ int part[1024];
    const int t = threadIdx.x;
    const int base = t * 128;
    int s = 0;
    for (int i = 0; i < 128; ++i) s += cnt[base + i];
    part[t] = s;
    __syncthreads();
    for (int off = 1; off < 1024; off <<= 1) {
        int v = (t >= off) ? part[t - off] : 0;
        __syncthreads();
        part[t] += v;
        __syncthreads();
    }
    int ex = (t == 0) ? 0 : part[t - 1];
    for (int i = 0; i < 128; ++i) { rowptr[base + i] = ex; ex += cnt[base + i]; }
    if (t == 1023) rowptr[NN] = ex;
}

__global__ void k_fill(const void* __restrict__ eidx, const int* __restrict__ flags,
                       const int* __restrict__ rowptr, int* __restrict__ fillp,
                       int* __restrict__ col) {
    int i = blockIdx.x * 256 + threadIdx.x;
    if (i >= NE) return;
    int e64 = flags[0];
    int s = geti(eidx, (size_t)i, e64);
    int d = geti(eidx, (size_t)NE + i, e64);
    int p = rowptr[d] + atomicAdd(&fillp[d], 1);
    col[p] = s;
}

// batch sorted: graph g spans rows [gstart[g], gstart[g+1])
__global__ void k_gstart(const void* __restrict__ batch, const int* __restrict__ flags,
                         int* __restrict__ gstart) {
    int i = blockIdx.x * 256 + threadIdx.x;
    if (i >= NN) return;
    int b64 = flags[1];
    int b = geti(batch, (size_t)i, b64);
    if (i == 0) {
        for (int g = 0; g <= b; ++g) gstart[g] = 0;
    } else {
        int pb = geti(batch, (size_t)i - 1, b64);
        for (int g = pb + 1; g <= b; ++g) gstart[g] = i;
    }
    if (i == NN - 1) {
        for (int g = b + 1; g <= NG; ++g) gstart[g] = NN;
    }
}

// ---------------- row load/store helpers. MODE: 0=bf16, 1=fp8, 2=fp32 ----------------
template<int D, int MODE>
__device__ __forceinline__ void load_row(const void* h, int sn, int c0, float* v) {
    constexpr int EPL = D / 64;
    if constexpr (MODE == 2) {                       // fp32
        const float* p = (const float*)h + (size_t)sn * D + c0;
#pragma unroll
        for (int i = 0; i < EPL; i += 2) {
            float2 u = *(const float2*)(p + i);
            v[i] = u.x; v[i + 1] = u.y;
        }
    } else if constexpr (MODE == 1) {                // fp8
        const unsigned char* p = (const unsigned char*)h + (size_t)sn * D + c0;
#if FP8_CVT_HW
        if constexpr (EPL == 8) {
            uint2 u = *(const uint2*)p;
            f32x2 a = __builtin_amdgcn_cvt_pk_f32_fp8((int)u.x, false);
            f32x2 b = __builtin_amdgcn_cvt_pk_f32_fp8((int)u.x, true);
            f32x2 c = __builtin_amdgcn_cvt_pk_f32_fp8((int)u.y, false);
            f32x2 d = __builtin_amdgcn_cvt_pk_f32_fp8((int)u.y, true);
            v[0] = a.x; v[1] = a.y; v[2] = b.x; v[3] = b.y;
            v[4] = c.x; v[5] = c.y; v[6] = d.x; v[7] = d.y;
        } else if constexpr (EPL == 4) {
            unsigned u = *(const unsigned*)p;
            f32x2 a = __builtin_amdgcn_cvt_pk_f32_fp8((int)u, false);
            f32x2 b = __builtin_amdgcn_cvt_pk_f32_fp8((int)u, true);
            v[0] = a.x; v[1] = a.y; v[2] = b.x; v[3] = b.y;
        } else {
            unsigned u = *(const unsigned short*)p;
            f32x2 a = __builtin_amdgcn_cvt_pk_f32_fp8((int)u, false);
            v[0] = a.x; v[1] = a.y;
        }
#else
        if constexpr (EPL == 8) {
            uint2 u = *(const uint2*)p;
#pragma unroll
            for (int i = 0; i < 4; ++i) v[i] = e4m32f((u.x >> (8 * i)) & 0xffu);
#pragma unroll
            for (int i = 0; i < 4; ++i) v[4 + i] = e4m32f((u.y >> (8 * i)) & 0xffu);
        } else if constexpr (EPL == 4) {
            unsigned u = *(const unsigned*)p;
#pragma unroll
            for (int i = 0; i < 4; ++i) v[i] = e4m32f((u >> (8 * i)) & 0xffu);
        } else {
            unsigned short u = *(const unsigned short*)p;
            v[0] = e4m32f(u & 0xffu); v[1] = e4m32f((u >> 8) & 0xffu);
        }
#endif
    } else {                                         // bf16
        const unsigned short* p = (const unsigned short*)h + (size_t)sn * D + c0;
        if constexpr (EPL == 8) {
            uint4 u = *(const uint4*)p;
            unsigned w[4] = {u.x, u.y, u.z, u.w};
#pragma unroll
            for (int i = 0; i < 4; ++i) { v[2 * i] = bfbits2f(w[i] & 0xffffu); v[2 * i + 1] = bfbits2f(w[i] >> 16); }
        } else if constexpr (EPL == 4) {
            uint2 u = *(const uint2*)p;
            v[0] = bfbits2f(u.x & 0xffffu); v[1] = bfbits2f(u.x >> 16);
            v[2] = bfbits2f(u.y & 0xffffu); v[3] = bfbits2f(u.y >> 16);
        } else {
            unsigned u = *(const unsigned*)p;
            v[0] = bfbits2f(u & 0xffffu); v[1] = bfbits2f(u >> 16);
        }
    }
}

template<int D, bool FP8>
__device__ __forceinline__ void store_row(void* out, int n, int c0, const float* v) {
    constexpr int EPL = D / 64;
    if constexpr (FP8) {
        unsigned char* p = (unsigned char*)out + (size_t)n * D + c0;
        if constexpr (EPL == 8) {
            uint2 u;
            u.x = enc4(v[0], v[1], v[2], v[3]);
            u.y = enc4(v[4], v[5], v[6], v[7]);
            *(uint2*)p = u;
        } else if constexpr (EPL == 4) {
            *(unsigned*)p = enc4(v[0], v[1], v[2], v[3]);
        } else {
            *(unsigned short*)p = (unsigned short)(enc1(v[0]) | (enc1(v[1]) << 8));
        }
    } else {
        unsigned short* p = (unsigned short*)out + (size_t)n * D + c0;
        if constexpr (EPL == 8) {
            uint4 u; u.x = pack2(v[0], v[1]); u.y = pack2(v[2], v[3]);
            u.z = pack2(v[4], v[5]); u.w = pack2(v[6], v[7]);
            *(uint4*)p = u;
        } else if constexpr (EPL == 4) {
            uint2 u; u.x = pack2(v[0], v[1]); u.y = pack2(v[2], v[3]);
            *(uint2*)p = u;
        } else {
            *(unsigned*)p = pack2(v[0], v[1]);
        }
    }
}

// ---------------- pull aggregation (CSR, fp32 reg accum) ----------------
template<int D, int IN_MODE, bool OUT_FP8, bool EPI>
__global__ __launch_bounds__(256) void k_agg(
    const void* __restrict__ h,
    const int* __restrict__ rowptr, const int* __restrict__ col,
    const float* __restrict__ dinv,
    const float* __restrict__ b, const float* __restrict__ s, const float* __restrict__ t,
    void* __restrict__ out)
{
    constexpr int EPL = D / 64;
    int n = (blockIdx.x * 256 + threadIdx.x) >> 6;
    int lane = threadIdx.x & 63;
    if (n >= NN) return;
    const int c0 = lane * EPL;
    float dn = dinv[n];
    float acc[EPL], vals[EPL];

    load_row<D, IN_MODE>(h, n, c0, vals);       // self loop: weight dinv[n]^2
    float wsl = dn * dn;
#pragma unroll
    for (int i = 0; i < EPL; ++i) acc[i] = vals[i] * wsl;

    int e1 = rowptr[n + 1];
    for (int e = rowptr[n]; e < e1; ++e) {
        int sn = col[e];
        float w = dinv[sn] * dn;
        load_row<D, IN_MODE>(h, sn, c0, vals);
#pragma unroll
        for (int i = 0; i < EPL; ++i) acc[i] += vals[i] * w;
    }

    if constexpr (EPI) {                        // layer-3 epilogue: bn(relu(z + bias))
#pragma unroll
        for (int i = 0; i < EPL; ++i) {
            int c = c0 + i;
            float z = acc[i] + b[c];
            z = fmaxf(z, 0.0f);
            acc[i] = s[c] * z + t[c];
        }
    }
    store_row<D, OUT_FP8>(out, n, c0, acc);
}

// ---------------- pooling: one wave per graph ----------------
__global__ void k_pool(const unsigned short* __restrict__ h3, const int* __restrict__ gstart,
                       unsigned short* __restrict__ pooled) {
    int g = (blockIdx.x * 256 + threadIdx.x) >> 6;
    int lane = threadIdx.x & 63;
    if (g >= NG) return;
    int r0 = gstart[g], r1 = gstart[g + 1];
    float a0 = 0, a1 = 0, a2 = 0, a3 = 0;
    for (int r = r0; r < r1; ++r) {
        uint2 u = *(const uint2*)(h3 + (size_t)r * 256 + lane * 4);
        a0 += bfbits2f(u.x & 0xffffu); a1 += bfbits2f(u.x >> 16);
        a2 += bfbits2f(u.y & 0xffffu); a3 += bfbits2f(u.y >> 16);
    }
    int c = r1 - r0;
    float inv = 1.0f / (float)(c > 0 ? c : 1);
    uint2 o;
    o.x = pack2(a0 * inv, a1 * inv);
    o.y = pack2(a2 * inv, a3 * inv);
    *(uint2*)(pooled + (size_t)g * 256 + lane * 4) = o;
}

// ---------------- MFMA GEMM: C[M,Ncols] = A[M,K] @ Wt[Ncols,K]^T, fused epilogue ----------------
// m97-style: global_load_lds staging into unpadded [128][32] tiles; fp8 A staged raw,
// decoded after fragment read via HW cvt (exact in bf16). OUT_MODE: 0=bf16, 1=fp8, 2=fp32.
template<bool A_FP8, int OUT_MODE, bool RELU, bool HAS_BN, bool HAS_BIAS>
__global__ __launch_bounds__(256)
void k_gemm(const void* __restrict__ Aptr,
            const unsigned short* __restrict__ Wt,
            const float* __restrict__ bias,
            const float* __restrict__ s, const float* __restrict__ t,
            void* __restrict__ Cptr,
            int K, int Ncols)
{
    __shared__ __align__(16) unsigned short lB[128 * 32];                 // 8 KB
    __shared__ __align__(16) unsigned char  lA8[A_FP8 ? 128 * 32 : 16];   // 4 KB raw fp8
    __shared__ __align__(16) unsigned short lA16[A_FP8 ? 8 : 128 * 32];   // 8 KB bf16
    const int tid = threadIdx.x;
    const int bm = blockIdx.y * 128;
    const int bn = blockIdx.x * 128;
    const int lane = tid & 63;
    const int wave = tid >> 6;
    const int wm = (wave >> 1) * 64;
    const int wn = (wave & 1) * 64;
    const int fr = lane & 15;
    const int fq = lane >> 4;

    f32x4 acc[4][4] = {};

    for (int k0 = 0; k0 < K; k0 += 32) {
        // ---- stage A ----
        if constexpr (A_FP8) {
            // wave w covers rows [w*32, w*32+32): lane -> row w*32 + lane/2, 16B half lane&1
            const unsigned char* g = (const unsigned char*)Aptr
                + (size_t)(bm + (wave << 5) + (lane >> 1)) * K + k0 + (lane & 1) * 16;
            gld16(g, &lA8[(wave << 5) * 32], lane);
        } else {
            const unsigned short* Ab = (const unsigned short*)Aptr;
#pragma unroll
            for (int c = 0; c < 2; ++c) {
                const unsigned short* g = Ab
                    + (size_t)(bm + (wave << 5) + (c << 4) + (lane >> 2)) * K + k0 + (lane & 3) * 8;
                gld16(g, &lA16[((wave << 5) + (c << 4)) * 32], lane);
            }
        }
        // ---- stage B (bf16 weights) ----
#pragma unroll
        for (int c = 0; c < 2; ++c) {
            const unsigned short* g = Wt
                + (size_t)(bn + (wave << 5) + (c << 4) + (lane >> 2)) * K + k0 + (lane & 3) * 8;
            gld16(g, &lB[((wave << 5) + (c << 4)) * 32], lane);
        }
        __syncthreads();

        short8 a[4], b[4];
#pragma unroll
        for (int i = 0; i < 4; ++i) {
            if constexpr (A_FP8)
                a[i] = dec8(*(const uint2*)&lA8[(wm + 16 * i + fr) * 32 + fq * 8]);
            else
                a[i] = *(const short8*)&lA16[(wm + 16 * i + fr) * 32 + fq * 8];
        }
#pragma unroll
        for (int j = 0; j < 4; ++j)
            b[j] = *(const short8*)&lB[(wn + 16 * j + fr) * 32 + fq * 8];
#pragma unroll
        for (int i = 0; i < 4; ++i)
#pragma unroll
            for (int j = 0; j < 4; ++j)
                acc[i][j] = __builtin_amdgcn_mfma_f32_16x16x32_bf16(a[i], b[j], acc[i][j], 0, 0, 0);
        __syncthreads();
    }

#pragma unroll
    for (int j = 0; j < 4; ++j) {
        int colI = bn + wn + 16 * j + fr;
        float bi = HAS_BIAS ? bias[colI] : 0.0f;
        float sc = HAS_BN ? s[colI] : 1.0f;
        float tc = HAS_BN ? t[colI] : 0.0f;
#pragma unroll
        for (int i = 0; i < 4; ++i) {
#pragma unroll
            for (int r = 0; r < 4; ++r) {
                int row = bm + wm + 16 * i + fq * 4 + r;
                float z = acc[i][j][r] + bi;
                if (RELU) z = fmaxf(z, 0.0f);
                float y = HAS_BN ? (sc * z + tc) : z;
                if constexpr (OUT_MODE == 2)
                    ((float*)Cptr)[(size_t)row * Ncols + colI] = y;
                else if constexpr (OUT_MODE == 1)
                    ((unsigned char*)Cptr)[(size_t)row * Ncols + colI] = (unsigned char)enc1(y);
                else
                    ((unsigned short*)Cptr)[(size_t)row * Ncols + colI] = f2bfbits(y);
            }
        }
    }
}

// ---------------- launch ----------------

extern "C" void kernel_launch(void* const* d_in, const int* in_sizes, int n_in,
                              void* d_out, int out_size, void* d_ws, size_t ws_size,
                              hipStream_t stream) {
    const float* x   = (const float*)d_in[0];      // fp32 per reference
    const void* eidx = d_in[1];
    const void* batch = d_in[2];
    const float* W1  = (const float*)d_in[3];
    const float* b1  = (const float*)d_in[4];
    const float* W2  = (const float*)d_in[5];
    const float* b2  = (const float*)d_in[6];
    const float* W3  = (const float*)d_in[7];
    const float* b3  = (const float*)d_in[8];
    const float* g1  = (const float*)d_in[9];
    const float* be1 = (const float*)d_in[10];
    const float* m1  = (const float*)d_in[11];
    const float* v1  = (const float*)d_in[12];
    const float* g2  = (const float*)d_in[13];
    const float* be2 = (const float*)d_in[14];
    const float* m2  = (const float*)d_in[15];
    const float* v2  = (const float*)d_in[16];
    const float* g3  = (const float*)d_in[17];
    const float* be3 = (const float*)d_in[18];
    const float* m3  = (const float*)d_in[19];
    const float* v3  = (const float*)d_in[20];
    const float* Wf1 = (const float*)d_in[21];
    const float* bf1 = (const float*)d_in[22];
    const float* Wf2 = (const float*)d_in[23];
    const float* bf2 = (const float*)d_in[24];

    // ---- fixed compact layout (~139.6 MiB, proven fault-free) ----
    unsigned char* RB = (unsigned char*)d_ws;            // 64 MiB: H1/H2 fp8 [NN,512]; later H3 bf16 [NN,256]
    unsigned char* RA = RB + 67108864;                   // 64 MiB: agg1 bf16 / agg2 fp8 / T3 bf16 / pooled+z1
    unsigned char* EX = RB + 134217728;                  // extras ~5.4 MiB
    int*   rowptr = (int*)(EX + 0);
    int*   col    = (int*)(EX + 524544);
    float* dinv   = (float*)(EX + 2621696);
    int*   cnt    = (int*)(EX + 3145984);
    int*   fillp  = (int*)(EX + 3670272);
    int*   gstart = (int*)(EX + 4194560);
    float* sbuf   = (float*)(EX + 4211456);
    float *s1 = sbuf, *t1 = sbuf + 512, *s2 = sbuf + 1024, *t2 = sbuf + 1536;
    float *s3 = sbuf + 2048, *t3v = sbuf + 2304;
    unsigned short* Wt1  = (unsigned short*)(EX + 4221696);  // [512,128] bf16
    unsigned short* Wt2  = (unsigned short*)(EX + 4352768);  // [512,512]
    unsigned short* Wt3  = (unsigned short*)(EX + 4877056);  // [256,512]
    unsigned short* Wtf1 = (unsigned short*)(EX + 5139200);  // [256,256]
    unsigned short* Wtf2 = (unsigned short*)(EX + 5270272);  // [256,256]
    int*   flags = (int*)(EX + 5401344);

    unsigned short* pooled = (unsigned short*)RA;            // [NG,256] bf16 (T3 dead)
    unsigned short* z1     = (unsigned short*)(RA + 2097152);

    // ---- prep ----
    k_detect<<<1, 1, 0, stream>>>(eidx, batch, flags);
    k_transpose<<<(128 * 512) / 256, 256, 0, stream>>>(W1, Wt1, 128, 512);
    k_transpose<<<(512 * 512) / 256, 256, 0, stream>>>(W2, Wt2, 512, 512);
    k_transpose<<<(512 * 256) / 256, 256, 0, stream>>>(W3, Wt3, 512, 256);
    k_transpose<<<(256 * 256) / 256, 256, 0, stream>>>(Wf1, Wtf1, 256, 256);
    k_transpose<<<(256 * 256) / 256, 256, 0, stream>>>(Wf2, Wtf2, 256, 256);
    k_bn_prep<<<2, 256, 0, stream>>>(g1, be1, m1, v1, s1, t1, 512);
    k_bn_prep<<<2, 256, 0, stream>>>(g2, be2, m2, v2, s2, t2, 512);
    k_bn_prep<<<1, 256, 0, stream>>>(g3, be3, m3, v3, s3, t3v, 256);
    k_zero<<<NN / 256, 256, 0, stream>>>(cnt, NN);
    k_zero<<<NN / 256, 256, 0, stream>>>(fillp, NN);
    k_deg_count<<<NE / 256, 256, 0, stream>>>(eidx, flags, cnt);
    k_dinv<<<NN / 256, 256, 0, stream>>>(cnt, dinv);
    k_scan<<<1, 1024, 0, stream>>>(cnt, rowptr);
    k_fill<<<NE / 256, 256, 0, stream>>>(eidx, flags, rowptr, fillp, col);
    k_gstart<<<NN / 256, 256, 0, stream>>>(batch, flags, gstart);

    const dim3 gagg(NN / 4), gpool(NG / 4);
    const dim3 ggA(4, NN / 128), ggB(2, NN / 128), ggh(2, NG / 128);

    // L1: agg x(fp32) @128 -> bf16 agg1 (RA); GEMM 128->512 +bias+relu+bn -> H1 fp8 (RB)
    k_agg<128, 2, false, false><<<gagg, 256, 0, stream>>>(x, rowptr, col, dinv, nullptr, nullptr, nullptr, RA);
    k_gemm<false, 1, true, true, true><<<ggA, 256, 0, stream>>>(RA, Wt1, b1, s1, t1, RB, 128, 512);

    // L2: agg H1(fp8) @512 -> agg2 fp8 (RA); GEMM 512->512 +epilogue -> H2 fp8 (RB)
    k_agg<512, 1, true, false><<<gagg, 256, 0, stream>>>(RB, rowptr, col, dinv, nullptr, nullptr, nullptr, RA);
    k_gemm<true, 1, true, true, true><<<ggA, 256, 0, stream>>>(RA, Wt2, b2, s2, t2, RB, 512, 512);

    // L3: GEMM 512->256 raw (H2 fp8 -> T3 bf16 in RA); agg @256 +fused epilogue -> H3 bf16 (RB)
    k_gemm<true, 0, false, false, false><<<ggB, 256, 0, stream>>>(RB, Wt3, nullptr, nullptr, nullptr, RA, 512, 256);
    k_agg<256, 0, false, true><<<gagg, 256, 0, stream>>>(RA, rowptr, col, dinv, b3, s3, t3v, RB);

    // pool (H3 in RB -> pooled bf16 in RA)
    k_pool<<<gpool, 256, 0, stream>>>((const unsigned short*)RB, gstart, pooled);

    // MLP head: z1 = relu(pooled@Wf1 + bf1); out(fp32) = z1@Wf2 + bf2
    k_gemm<false, 0, true, false, true><<<ggh, 256, 0, stream>>>(pooled, Wtf1, bf1, nullptr, nullptr, z1, 256, 256);
    k_gemm<false, 2, false, false, true><<<ggh, 256, 0, stream>>>(z1, Wtf2, bf2, nullptr, nullptr, d_out, 256, 256);
}

// Round 8
// 697.023 us; speedup vs baseline: 1.3943x; 1.1291x over previous
//
#include <hip/hip_runtime.h>

static constexpr int NN = 131072;   // nodes
static constexpr int NE = 524288;   // edges
static constexpr int NG = 4096;     // graphs

typedef __attribute__((ext_vector_type(8))) short short8;
typedef __attribute__((ext_vector_type(4))) float f32x4;
typedef __attribute__((ext_vector_type(2))) float f32x2;

__device__ __forceinline__ float bfbits2f(unsigned b) {
    return __uint_as_float(b << 16);
}
__device__ __forceinline__ unsigned short f2bfbits(float f) {
    unsigned u = __float_as_uint(f);
    u += 0x7fffu + ((u >> 16) & 1u);   // RNE
    return (unsigned short)(u >> 16);
}
__device__ __forceinline__ unsigned pack2(float a, float b) {
    return (unsigned)f2bfbits(a) | ((unsigned)f2bfbits(b) << 16);
}

// dual-width integer read (robust to int32 or int64 index tensors)
__device__ __forceinline__ int geti(const void* p, size_t i, int w64) {
    return w64 ? (int)((const long long*)p)[i] : ((const int*)p)[i];
}

#if __has_builtin(__builtin_amdgcn_cvt_pk_f32_fp8) && __has_builtin(__builtin_amdgcn_cvt_pk_fp8_f32)
#define FP8_CVT_HW 1
#else
#define FP8_CVT_HW 0
#endif

// ---- software OCP e4m3 codec (fallback) ----
__device__ __forceinline__ float e4m32f(unsigned b) {
    unsigned e = (b >> 3) & 0xFu, m = b & 7u;
    float v = e ? __uint_as_float(((e + 120u) << 23) | (m << 20))
                : (float)m * 0.001953125f;            // m * 2^-9
    return (b & 0x80u) ? -v : v;
}
__device__ __forceinline__ unsigned f2e4m3(float f) {
    unsigned u = __float_as_uint(f);
    unsigned s = (u >> 24) & 0x80u;
    unsigned mag = u & 0x7fffffffu;
    if (mag >= 0x43e00000u) return s | 0x7eu;          // clamp to +-448
    if (mag < 0x3c800000u) {                           // |f| < 2^-6 -> subnormal
        int q = (int)(__uint_as_float(mag) * 512.0f + 0.5f);   // 0..8
        return s | (unsigned)q;
    }
    unsigned r = mag + 0x0007ffffu + ((mag >> 20) & 1u);       // RNE to 3 mant bits
    if (r >= 0x43e00000u) return s | 0x7eu;
    return s | (((r >> 23) - 120u) << 3) | ((r >> 20) & 7u);
}

// 2 fp8 (byte pair HI of dword w) -> packed bf16 dword. HI must be immediate.
template<bool HI>
__device__ __forceinline__ unsigned dec_pair(unsigned w) {
#if FP8_CVT_HW
    f32x2 p = __builtin_amdgcn_cvt_pk_f32_fp8((int)w, HI);
    return __builtin_amdgcn_perm(__float_as_uint(p.y), __float_as_uint(p.x), 0x07060302u);
#else
    unsigned b0 = HI ? ((w >> 16) & 255u) : (w & 255u);
    unsigned b1 = HI ? (w >> 24) : ((w >> 8) & 255u);
    return pack2(e4m32f(b0), e4m32f(b1));
#endif
}

// 8 fp8 -> short8 bf16 fragment
__device__ __forceinline__ short8 dec8(uint2 u) {
    union { uint4 q; short8 s; } r;
    r.q.x = dec_pair<false>(u.x);
    r.q.y = dec_pair<true>(u.x);
    r.q.z = dec_pair<false>(u.y);
    r.q.w = dec_pair<true>(u.y);
    return r.s;
}

__device__ __forceinline__ unsigned enc4(float a, float b, float c, float d) {
#if FP8_CVT_HW
    int r = __builtin_amdgcn_cvt_pk_fp8_f32(a, b, 0, false);
    r = __builtin_amdgcn_cvt_pk_fp8_f32(c, d, r, true);
    return (unsigned)r;
#else
    return f2e4m3(a) | (f2e4m3(b) << 8) | (f2e4m3(c) << 16) | (f2e4m3(d) << 24);
#endif
}
__device__ __forceinline__ unsigned enc1(float a) {
#if FP8_CVT_HW
    return (unsigned)__builtin_amdgcn_cvt_pk_fp8_f32(a, a, 0, false) & 0xffu;
#else
    return f2e4m3(a);
#endif
}

// async global->LDS, 16B/lane; data lands at l + lane*16
__device__ __forceinline__ void gld16(const void* g, void* l, int lane) {
#if __has_builtin(__builtin_amdgcn_global_load_lds)
    __builtin_amdgcn_global_load_lds((const __attribute__((address_space(1))) unsigned int*)g,
                                     (__attribute__((address_space(3))) unsigned int*)l, 16, 0, 0);
#else
    *(uint4*)((char*)l + lane * 16) = *(const uint4*)g;
#endif
}

// ---------------- detect int width (int64 => odd int32 halves are zero) ----------------
__global__ void k_detect(const void* __restrict__ eidx, const void* __restrict__ batch,
                         int* __restrict__ flags) {
    const int* e32 = (const int*)eidx;
    const int* b32 = (const int*)batch;
    int e64 = (e32[1] == 0 && e32[2001] == 0 && e32[40001] == 0 && e32[2 * NE - 1] == 0) ? 1 : 0;
    int b64 = (b32[NN - 1] == 0) ? 1 : 0;
    flags[0] = e64;
    flags[1] = b64;
}

// ---------------- small prep kernels ----------------

__global__ void k_zero(int* __restrict__ p, int n) {
    int i = blockIdx.x * 256 + threadIdx.x;
    if (i < n) p[i] = 0;
}

// fp32 W[K,Ncols] -> bf16 Wt[Ncols,K]
__global__ void k_transpose(const float* __restrict__ W,
                            unsigned short* __restrict__ Wt, int K, int Ncols) {
    int idx = blockIdx.x * 256 + threadIdx.x;
    if (idx >= K * Ncols) return;
    int k = idx / Ncols, n = idx - k * Ncols;
    Wt[n * K + k] = f2bfbits(W[idx]);
}

__global__ void k_bn_prep(const float* __restrict__ g, const float* __restrict__ be,
                          const float* __restrict__ m, const float* __restrict__ v,
                          float* __restrict__ s, float* __restrict__ t, int d) {
    int i = blockIdx.x * 256 + threadIdx.x;
    if (i >= d) return;
    float inv = rsqrtf(v[i] + 1e-5f);
    float sc = g[i] * inv;
    s[i] = sc;
    t[i] = be[i] - m[i] * sc;
}

__global__ void k_deg_count(const void* __restrict__ eidx, const int* __restrict__ flags,
                            int* __restrict__ cnt) {
    int i = blockIdx.x * 256 + threadIdx.x;
    if (i >= NE) return;
    int d = geti(eidx, (size_t)NE + i, flags[0]);
    atomicAdd(&cnt[d], 1);
}

// single-block exclusive scan of cnt[NN] -> rowptr[NN+1]; fused dinv = rsqrt(cnt+1)
__global__ __launch_bounds__(1024) void k_scan(const int* __restrict__ cnt, int* __restrict__ rowptr,
                                               float* __restrict__ dinv) {
    __shared__ int part[1024];
    const int t = threadIdx.x;
    const int base = t * 128;
    const int4* c4 = (const int4*)(cnt + base);
    int s = 0;
#pragma unroll
    for (int i = 0; i < 32; ++i) { int4 u = c4[i]; s += u.x + u.y + u.z + u.w; }
    part[t] = s;
    __syncthreads();
    for (int off = 1; off < 1024; off <<= 1) {
        int v = (t >= off) ? part[t - off] : 0;
        __syncthreads();
        part[t] += v;
        __syncthreads();
    }
    int ex = (t == 0) ? 0 : part[t - 1];
#pragma unroll
    for (int i = 0; i < 32; ++i) {
        int4 u = c4[i];
        int4 o; o.x = ex; o.y = ex + u.x; o.z = o.y + u.y; o.w = o.z + u.z; ex = o.w + u.w;
        *(int4*)(rowptr + base + 4 * i) = o;
        float4 dv;
        dv.x = rsqrtf((float)(u.x + 1)); dv.y = rsqrtf((float)(u.y + 1));
        dv.z = rsqrtf((float)(u.z + 1)); dv.w = rsqrtf((float)(u.w + 1));
        *(float4*)(dinv + base + 4 * i) = dv;
    }
    if (t == 1023) rowptr[NN] = ex;
}

__global__ void k_fill(const void* __restrict__ eidx, const int* __restrict__ flags,
                       const int* __restrict__ rowptr, int* __restrict__ fillp,
                       int* __restrict__ col) {
    int i = blockIdx.x * 256 + threadIdx.x;
    if (i >= NE) return;
    int e64 = flags[0];
    int s = geti(eidx, (size_t)i, e64);
    int d = geti(eidx, (size_t)NE + i, e64);
    int p = rowptr[d] + atomicAdd(&fillp[d], 1);
    col[p] = s;
}

// batch sorted: graph g spans rows [gstart[g], gstart[g+1])
__global__ void k_gstart(const void* __restrict__ batch, const int* __restrict__ flags,
                         int* __restrict__ gstart) {
    int i = blockIdx.x * 256 + threadIdx.x;
    if (i >= NN) return;
    int b64 = flags[1];
    int b = geti(batch, (size_t)i, b64);
    if (i == 0) {
        for (int g = 0; g <= b; ++g) gstart[g] = 0;
    } else {
        int pb = geti(batch, (size_t)i - 1, b64);
        for (int g = pb + 1; g <= b; ++g) gstart[g] = i;
    }
    if (i == NN - 1) {
        for (int g = b + 1; g <= NG; ++g) gstart[g] = NN;
    }
}

// ---------------- row load/store helpers. MODE: 0=bf16, 1=fp8, 2=fp32 ----------------
template<int D, int MODE>
__device__ __forceinline__ void load_row(const void* h, int sn, int c0, float* v) {
    constexpr int EPL = D / 64;
    if constexpr (MODE == 2) {                       // fp32
        const float* p = (const float*)h + (size_t)sn * D + c0;
#pragma unroll
        for (int i = 0; i < EPL; i += 2) {
            float2 u = *(const float2*)(p + i);
            v[i] = u.x; v[i + 1] = u.y;
        }
    } else if constexpr (MODE == 1) {                // fp8
        const unsigned char* p = (const unsigned char*)h + (size_t)sn * D + c0;
#if FP8_CVT_HW
        if constexpr (EPL == 8) {
            uint2 u = *(const uint2*)p;
            f32x2 a = __builtin_amdgcn_cvt_pk_f32_fp8((int)u.x, false);
            f32x2 b = __builtin_amdgcn_cvt_pk_f32_fp8((int)u.x, true);
            f32x2 c = __builtin_amdgcn_cvt_pk_f32_fp8((int)u.y, false);
            f32x2 d = __builtin_amdgcn_cvt_pk_f32_fp8((int)u.y, true);
            v[0] = a.x; v[1] = a.y; v[2] = b.x; v[3] = b.y;
            v[4] = c.x; v[5] = c.y; v[6] = d.x; v[7] = d.y;
        } else if constexpr (EPL == 4) {
            unsigned u = *(const unsigned*)p;
            f32x2 a = __builtin_amdgcn_cvt_pk_f32_fp8((int)u, false);
            f32x2 b = __builtin_amdgcn_cvt_pk_f32_fp8((int)u, true);
            v[0] = a.x; v[1] = a.y; v[2] = b.x; v[3] = b.y;
        } else {
            unsigned u = *(const unsigned short*)p;
            f32x2 a = __builtin_amdgcn_cvt_pk_f32_fp8((int)u, false);
            v[0] = a.x; v[1] = a.y;
        }
#else
        if constexpr (EPL == 8) {
            uint2 u = *(const uint2*)p;
#pragma unroll
            for (int i = 0; i < 4; ++i) v[i] = e4m32f((u.x >> (8 * i)) & 0xffu);
#pragma unroll
            for (int i = 0; i < 4; ++i) v[4 + i] = e4m32f((u.y >> (8 * i)) & 0xffu);
        } else if constexpr (EPL == 4) {
            unsigned u = *(const unsigned*)p;
#pragma unroll
            for (int i = 0; i < 4; ++i) v[i] = e4m32f((u >> (8 * i)) & 0xffu);
        } else {
            unsigned short u = *(const unsigned short*)p;
            v[0] = e4m32f(u & 0xffu); v[1] = e4m32f((u >> 8) & 0xffu);
        }
#endif
    } else {                                         // bf16
        const unsigned short* p = (const unsigned short*)h + (size_t)sn * D + c0;
        if constexpr (EPL == 8) {
            uint4 u = *(const uint4*)p;
            unsigned w[4] = {u.x, u.y, u.z, u.w};
#pragma unroll
            for (int i = 0; i < 4; ++i) { v[2 * i] = bfbits2f(w[i] & 0xffffu); v[2 * i + 1] = bfbits2f(w[i] >> 16); }
        } else if constexpr (EPL == 4) {
            uint2 u = *(const uint2*)p;
            v[0] = bfbits2f(u.x & 0xffffu); v[1] = bfbits2f(u.x >> 16);
            v[2] = bfbits2f(u.y & 0xffffu); v[3] = bfbits2f(u.y >> 16);
        } else {
            unsigned u = *(const unsigned*)p;
            v[0] = bfbits2f(u & 0xffffu); v[1] = bfbits2f(u >> 16);
        }
    }
}

template<int D, bool FP8>
__device__ __forceinline__ void store_row(void* out, int n, int c0, const float* v) {
    constexpr int EPL = D / 64;
    if constexpr (FP8) {
        unsigned char* p = (unsigned char*)out + (size_t)n * D + c0;
        if constexpr (EPL == 8) {
            uint2 u;
            u.x = enc4(v[0], v[1], v[2], v[3]);
            u.y = enc4(v[4], v[5], v[6], v[7]);
            *(uint2*)p = u;
        } else if constexpr (EPL == 4) {
            *(unsigned*)p = enc4(v[0], v[1], v[2], v[3]);
        } else {
            *(unsigned short*)p = (unsigned short)(enc1(v[0]) | (enc1(v[1]) << 8));
        }
    } else {
        unsigned short* p = (unsigned short*)out + (size_t)n * D + c0;
        if constexpr (EPL == 8) {
            uint4 u; u.x = pack2(v[0], v[1]); u.y = pack2(v[2], v[3]);
            u.z = pack2(v[4], v[5]); u.w = pack2(v[6], v[7]);
            *(uint4*)p = u;
        } else if constexpr (EPL == 4) {
            uint2 u; u.x = pack2(v[0], v[1]); u.y = pack2(v[2], v[3]);
            *(uint2*)p = u;
        } else {
            *(unsigned*)p = pack2(v[0], v[1]);
        }
    }
}

// ---------------- pull aggregation (CSR, fp32 reg accum, 2-edge unrolled for ILP) ----------------
template<int D, int IN_MODE, bool OUT_FP8>
__global__ __launch_bounds__(256) void k_agg(
    const void* __restrict__ h,
    const int* __restrict__ rowptr, const int* __restrict__ col,
    const float* __restrict__ dinv,
    void* __restrict__ out)
{
    constexpr int EPL = D / 64;
    int n = (blockIdx.x * 256 + threadIdx.x) >> 6;
    int lane = threadIdx.x & 63;
    if (n >= NN) return;
    const int c0 = lane * EPL;
    float dn = dinv[n];
    float acc[EPL], va[EPL], vb[EPL];

    load_row<D, IN_MODE>(h, n, c0, va);       // self loop: weight dinv[n]^2
    float wsl = dn * dn;
#pragma unroll
    for (int i = 0; i < EPL; ++i) acc[i] = va[i] * wsl;

    int e = rowptr[n], e1 = rowptr[n + 1];
    for (; e + 2 <= e1; e += 2) {
        int sa = col[e], sb = col[e + 1];
        float wa = dinv[sa] * dn, wb = dinv[sb] * dn;
        load_row<D, IN_MODE>(h, sa, c0, va);
        load_row<D, IN_MODE>(h, sb, c0, vb);
#pragma unroll
        for (int i = 0; i < EPL; ++i) acc[i] += va[i] * wa + vb[i] * wb;
    }
    if (e < e1) {
        int sa = col[e];
        float wa = dinv[sa] * dn;
        load_row<D, IN_MODE>(h, sa, c0, va);
#pragma unroll
        for (int i = 0; i < EPL; ++i) acc[i] += va[i] * wa;
    }
    store_row<D, OUT_FP8>(out, n, c0, acc);
}

// ---------------- fused layer-3 aggregation + epilogue + mean pool ----------------
// one block (4 waves) per graph; nodes are contiguous rows [gstart[g], gstart[g+1]).
// per node: agg over CSR at D=256 (bf16 T3), bn3(relu(+b3)), accumulate pooled mean.
__global__ __launch_bounds__(256) void k_agg_pool(
    const unsigned short* __restrict__ T3,
    const int* __restrict__ rowptr, const int* __restrict__ col,
    const float* __restrict__ dinv,
    const float* __restrict__ b, const float* __restrict__ s, const float* __restrict__ t,
    const int* __restrict__ gstart, unsigned short* __restrict__ pooled)
{
    __shared__ float red[4][256];
    const int g = blockIdx.x;
    const int wave = threadIdx.x >> 6, lane = threadIdx.x & 63;
    const int c0 = lane * 4;
    const int r0 = gstart[g], r1 = gstart[g + 1];
    float p0 = 0, p1 = 0, p2 = 0, p3 = 0;
    const float bc0 = b[c0], bc1 = b[c0 + 1], bc2 = b[c0 + 2], bc3 = b[c0 + 3];
    const float sc0 = s[c0], sc1 = s[c0 + 1], sc2 = s[c0 + 2], sc3 = s[c0 + 3];
    const float tc0 = t[c0], tc1 = t[c0 + 1], tc2 = t[c0 + 2], tc3 = t[c0 + 3];

    for (int n = r0 + wave; n < r1; n += 4) {
        float dn = dinv[n];
        float a0, a1, a2, a3;
        {
            uint2 u = *(const uint2*)(T3 + (size_t)n * 256 + c0);
            float w = dn * dn;
            a0 = bfbits2f(u.x & 0xffffu) * w; a1 = bfbits2f(u.x >> 16) * w;
            a2 = bfbits2f(u.y & 0xffffu) * w; a3 = bfbits2f(u.y >> 16) * w;
        }
        int e = rowptr[n], e1 = rowptr[n + 1];
        for (; e + 2 <= e1; e += 2) {
            int sa = col[e], sb = col[e + 1];
            float wa = dinv[sa] * dn, wb = dinv[sb] * dn;
            uint2 ua = *(const uint2*)(T3 + (size_t)sa * 256 + c0);
            uint2 ub = *(const uint2*)(T3 + (size_t)sb * 256 + c0);
            a0 += bfbits2f(ua.x & 0xffffu) * wa + bfbits2f(ub.x & 0xffffu) * wb;
            a1 += bfbits2f(ua.x >> 16) * wa + bfbits2f(ub.x >> 16) * wb;
            a2 += bfbits2f(ua.y & 0xffffu) * wa + bfbits2f(ub.y & 0xffffu) * wb;
            a3 += bfbits2f(ua.y >> 16) * wa + bfbits2f(ub.y >> 16) * wb;
        }
        if (e < e1) {
            int sa = col[e];
            float wa = dinv[sa] * dn;
            uint2 ua = *(const uint2*)(T3 + (size_t)sa * 256 + c0);
            a0 += bfbits2f(ua.x & 0xffffu) * wa; a1 += bfbits2f(ua.x >> 16) * wa;
            a2 += bfbits2f(ua.y & 0xffffu) * wa; a3 += bfbits2f(ua.y >> 16) * wa;
        }
        // bn3(relu(a + b3))
        p0 += sc0 * fmaxf(a0 + bc0, 0.0f) + tc0;
        p1 += sc1 * fmaxf(a1 + bc1, 0.0f) + tc1;
        p2 += sc2 * fmaxf(a2 + bc2, 0.0f) + tc2;
        p3 += sc3 * fmaxf(a3 + bc3, 0.0f) + tc3;
    }
    red[wave][c0] = p0; red[wave][c0 + 1] = p1; red[wave][c0 + 2] = p2; red[wave][c0 + 3] = p3;
    __syncthreads();
    int ch = threadIdx.x;
    float tot = red[0][ch] + red[1][ch] + red[2][ch] + red[3][ch];
    __syncthreads();
    red[0][ch] = tot;
    __syncthreads();
    if (ch < 128) {
        int ccount = r1 - r0;
        float inv = 1.0f / (float)(ccount > 0 ? ccount : 1);
        pooled[(size_t)g * 256 + 2 * ch] = f2bfbits(red[0][2 * ch] * inv);
        pooled[(size_t)g * 256 + 2 * ch + 1] = f2bfbits(red[0][2 * ch + 1] * inv);
    }
}

// ---------------- MFMA GEMM: C[M,Ncols] = A[M,K] @ Wt[Ncols,K]^T, fused epilogue ----------------
// m97-style [128][32] tiles (conflict-floor geometry), global_load_lds staging.
// DEEP: BK=64 via two sub-tiles per barrier (halves barrier drains).
// 1D grid with XCD swizzle: id%8 == rowblock%8 -> column-blocks sharing A land on one XCD.
// CB = column blocks (Ncols/128). OUT_MODE: 0=bf16, 1=fp8, 2=fp32.
template<bool A_FP8, bool DEEP, int CB, int OUT_MODE, bool RELU, bool HAS_BN, bool HAS_BIAS>
__global__ __launch_bounds__(256)
void k_gemm(const void* __restrict__ Aptr,
            const unsigned short* __restrict__ Wt,
            const float* __restrict__ bias,
            const float* __restrict__ s, const float* __restrict__ t,
            void* __restrict__ Cptr,
            int K, int Ncols)
{
    constexpr int NH = DEEP ? 2 : 1;
    __shared__ __align__(16) unsigned short lB[NH][128 * 32];
    __shared__ __align__(16) unsigned char  lA8[A_FP8 ? NH : 1][A_FP8 ? 128 * 32 : 16];
    __shared__ __align__(16) unsigned short lA16[A_FP8 ? 1 : NH][A_FP8 ? 8 : 128 * 32];
    const int tid = threadIdx.x;
    // XCD swizzle decode: r%8 == blockIdx.x%8 (requires rowblocks % 8 == 0)
    const int id = blockIdx.x;
    const int hi = id >> 3;
    const int cblk = hi % CB;
    const int rblk = (hi / CB) * 8 + (id & 7);
    const int bm = rblk * 128;
    const int bn = cblk * 128;
    const int lane = tid & 63;
    const int wave = tid >> 6;
    const int wm = (wave >> 1) * 64;
    const int wn = (wave & 1) * 64;
    const int fr = lane & 15;
    const int fq = lane >> 4;

    f32x4 acc[4][4] = {};

    for (int k0 = 0; k0 < K; k0 += 32 * NH) {
#pragma unroll
        for (int h = 0; h < NH; ++h) {
            const int kh = k0 + h * 32;
            // ---- stage A ----
            if constexpr (A_FP8) {
                const unsigned char* g = (const unsigned char*)Aptr
                    + (size_t)(bm + (wave << 5) + (lane >> 1)) * K + kh + (lane & 1) * 16;
                gld16(g, &lA8[h][(wave << 5) * 32], lane);
            } else {
                const unsigned short* Ab = (const unsigned short*)Aptr;
#pragma unroll
                for (int c = 0; c < 2; ++c) {
                    const unsigned short* g = Ab
                        + (size_t)(bm + (wave << 5) + (c << 4) + (lane >> 2)) * K + kh + (lane & 3) * 8;
                    gld16(g, &lA16[h][((wave << 5) + (c << 4)) * 32], lane);
                }
            }
            // ---- stage B (bf16 weights) ----
#pragma unroll
            for (int c = 0; c < 2; ++c) {
                const unsigned short* g = Wt
                    + (size_t)(bn + (wave << 5) + (c << 4) + (lane >> 2)) * K + kh + (lane & 3) * 8;
                gld16(g, &lB[h][((wave << 5) + (c << 4)) * 32], lane);
            }
        }
        __syncthreads();

#pragma unroll
        for (int h = 0; h < NH; ++h) {
            short8 a[4], b[4];
#pragma unroll
            for (int i = 0; i < 4; ++i) {
                if constexpr (A_FP8)
                    a[i] = dec8(*(const uint2*)&lA8[h][(wm + 16 * i + fr) * 32 + fq * 8]);
                else
                    a[i] = *(const short8*)&lA16[h][(wm + 16 * i + fr) * 32 + fq * 8];
            }
#pragma unroll
            for (int j = 0; j < 4; ++j)
                b[j] = *(const short8*)&lB[h][(wn + 16 * j + fr) * 32 + fq * 8];
#pragma unroll
            for (int i = 0; i < 4; ++i)
#pragma unroll
                for (int j = 0; j < 4; ++j)
                    acc[i][j] = __builtin_amdgcn_mfma_f32_16x16x32_bf16(a[i], b[j], acc[i][j], 0, 0, 0);
        }
        __syncthreads();
    }

#pragma unroll
    for (int j = 0; j < 4; ++j) {
        int colI = bn + wn + 16 * j + fr;
        float bi = HAS_BIAS ? bias[colI] : 0.0f;
        float sc = HAS_BN ? s[colI] : 1.0f;
        float tc = HAS_BN ? t[colI] : 0.0f;
#pragma unroll
        for (int i = 0; i < 4; ++i) {
#pragma unroll
            for (int r = 0; r < 4; ++r) {
                int row = bm + wm + 16 * i + fq * 4 + r;
                float z = acc[i][j][r] + bi;
                if (RELU) z = fmaxf(z, 0.0f);
                float y = HAS_BN ? (sc * z + tc) : z;
                if constexpr (OUT_MODE == 2)
                    ((float*)Cptr)[(size_t)row * Ncols + colI] = y;
                else if constexpr (OUT_MODE == 1)
                    ((unsigned char*)Cptr)[(size_t)row * Ncols + colI] = (unsigned char)enc1(y);
                else
                    ((unsigned short*)Cptr)[(size_t)row * Ncols + colI] = f2bfbits(y);
            }
        }
    }
}

// ---------------- launch ----------------

extern "C" void kernel_launch(void* const* d_in, const int* in_sizes, int n_in,
                              void* d_out, int out_size, void* d_ws, size_t ws_size,
                              hipStream_t stream) {
    const float* x   = (const float*)d_in[0];      // fp32 per reference
    const void* eidx = d_in[1];
    const void* batch = d_in[2];
    const float* W1  = (const float*)d_in[3];
    const float* b1  = (const float*)d_in[4];
    const float* W2  = (const float*)d_in[5];
    const float* b2  = (const float*)d_in[6];
    const float* W3  = (const float*)d_in[7];
    const float* b3  = (const float*)d_in[8];
    const float* g1  = (const float*)d_in[9];
    const float* be1 = (const float*)d_in[10];
    const float* m1  = (const float*)d_in[11];
    const float* v1  = (const float*)d_in[12];
    const float* g2  = (const float*)d_in[13];
    const float* be2 = (const float*)d_in[14];
    const float* m2  = (const float*)d_in[15];
    const float* v2  = (const float*)d_in[16];
    const float* g3  = (const float*)d_in[17];
    const float* be3 = (const float*)d_in[18];
    const float* m3  = (const float*)d_in[19];
    const float* v3  = (const float*)d_in[20];
    const float* Wf1 = (const float*)d_in[21];
    const float* bf1 = (const float*)d_in[22];
    const float* Wf2 = (const float*)d_in[23];
    const float* bf2 = (const float*)d_in[24];

    // ---- fixed compact layout (~139.6 MiB, proven fault-free) ----
    unsigned char* RB = (unsigned char*)d_ws;            // 64 MiB: H1/H2 fp8 [NN,512]; later pooled/z1
    unsigned char* RA = RB + 67108864;                   // 64 MiB: agg1 bf16 / agg2 fp8 / T3 bf16
    unsigned char* EX = RB + 134217728;                  // extras ~5.4 MiB
    int*   rowptr = (int*)(EX + 0);
    int*   col    = (int*)(EX + 524544);
    float* dinv   = (float*)(EX + 2621696);
    int*   cnt    = (int*)(EX + 3145984);
    int*   fillp  = (int*)(EX + 3670272);
    int*   gstart = (int*)(EX + 4194560);
    float* sbuf   = (float*)(EX + 4211456);
    float *s1 = sbuf, *t1 = sbuf + 512, *s2 = sbuf + 1024, *t2 = sbuf + 1536;
    float *s3 = sbuf + 2048, *t3v = sbuf + 2304;
    unsigned short* Wt1  = (unsigned short*)(EX + 4221696);  // [512,128] bf16
    unsigned short* Wt2  = (unsigned short*)(EX + 4352768);  // [512,512]
    unsigned short* Wt3  = (unsigned short*)(EX + 4877056);  // [256,512]
    unsigned short* Wtf1 = (unsigned short*)(EX + 5139200);  // [256,256]
    unsigned short* Wtf2 = (unsigned short*)(EX + 5270272);  // [256,256]
    int*   flags = (int*)(EX + 5401344);

    unsigned short* pooled = (unsigned short*)RB;            // [NG,256] bf16 (H2 dead after GEMM3)
    unsigned short* z1     = (unsigned short*)(RB + 2097152);

    // ---- prep ----
    k_detect<<<1, 1, 0, stream>>>(eidx, batch, flags);
    k_transpose<<<(128 * 512) / 256, 256, 0, stream>>>(W1, Wt1, 128, 512);
    k_transpose<<<(512 * 512) / 256, 256, 0, stream>>>(W2, Wt2, 512, 512);
    k_transpose<<<(512 * 256) / 256, 256, 0, stream>>>(W3, Wt3, 512, 256);
    k_transpose<<<(256 * 256) / 256, 256, 0, stream>>>(Wf1, Wtf1, 256, 256);
    k_transpose<<<(256 * 256) / 256, 256, 0, stream>>>(Wf2, Wtf2, 256, 256);
    k_bn_prep<<<2, 256, 0, stream>>>(g1, be1, m1, v1, s1, t1, 512);
    k_bn_prep<<<2, 256, 0, stream>>>(g2, be2, m2, v2, s2, t2, 512);
    k_bn_prep<<<1, 256, 0, stream>>>(g3, be3, m3, v3, s3, t3v, 256);
    k_zero<<<NN / 256, 256, 0, stream>>>(cnt, NN);
    k_zero<<<NN / 256, 256, 0, stream>>>(fillp, NN);
    k_deg_count<<<NE / 256, 256, 0, stream>>>(eidx, flags, cnt);
    k_scan<<<1, 1024, 0, stream>>>(cnt, rowptr, dinv);
    k_fill<<<NE / 256, 256, 0, stream>>>(eidx, flags, rowptr, fillp, col);
    k_gstart<<<NN / 256, 256, 0, stream>>>(batch, flags, gstart);

    const dim3 gagg(NN / 4);

    // L1: agg x(fp32) @128 -> bf16 agg1 (RA); GEMM 128->512 +bias+relu+bn -> H1 fp8 (RB)
    k_agg<128, 2, false><<<gagg, 256, 0, stream>>>(x, rowptr, col, dinv, RA);
    k_gemm<false, false, 4, 1, true, true, true><<<4096, 256, 0, stream>>>(RA, Wt1, b1, s1, t1, RB, 128, 512);

    // L2: agg H1(fp8) @512 -> agg2 fp8 (RA); GEMM 512->512 (DEEP) +epilogue -> H2 fp8 (RB)
    k_agg<512, 1, true><<<gagg, 256, 0, stream>>>(RB, rowptr, col, dinv, RA);
    k_gemm<true, true, 4, 1, true, true, true><<<4096, 256, 0, stream>>>(RA, Wt2, b2, s2, t2, RB, 512, 512);

    // L3: GEMM 512->256 raw (DEEP, H2 fp8 -> T3 bf16 in RA)
    k_gemm<true, true, 2, 0, false, false, false><<<2048, 256, 0, stream>>>(RB, Wt3, nullptr, nullptr, nullptr, RA, 512, 256);

    // fused: agg @256 + bn3(relu(+b3)) + mean pool -> pooled bf16 (RB; H2 dead)
    k_agg_pool<<<NG, 256, 0, stream>>>((const unsigned short*)RA, rowptr, col, dinv,
                                       b3, s3, t3v, gstart, pooled);

    // MLP head: z1 = relu(pooled@Wf1 + bf1); out(fp32) = z1@Wf2 + bf2
    k_gemm<false, false, 2, 0, true, false, true><<<64, 256, 0, stream>>>(pooled, Wtf1, bf1, nullptr, nullptr, z1, 256, 256);
    k_gemm<false, false, 2, 2, false, false, true><<<64, 256, 0, stream>>>(z1, Wtf2, bf2, nullptr, nullptr, d_out, 256, 256);
}